// Round 2
// baseline (587.017 us; speedup 1.0000x reference)
//
#include <hip/hip_runtime.h>
#include <hip/hip_bf16.h>

typedef __attribute__((ext_vector_type(8))) short bf16x8;
typedef __attribute__((ext_vector_type(4))) float f32x4;

#define AS1C(p) ((const __attribute__((address_space(1))) void*)(p))
#define AS3(p)  ((__attribute__((address_space(3))) void*)(p))

// ---------------------------------------------------------------------------
// Kernel 1: Hadamard-rotate (FWHT/sqrt(32)) + MXFP4 quant-dequant -> bf16
// 8 lanes per group, 4 elements per lane. Loads: lane-contiguous float4
// (fully coalesced). FWHT stages 1-2 in-register, stages 4/8/16 via
// __shfl_xor(1/2/4). amax: 3-step shfl_xor max. Stores: contiguous ushort4.
// ---------------------------------------------------------------------------
__global__ void rotquant_kernel(const float* __restrict__ in,
                                unsigned short* __restrict__ out,
                                size_t nslots /* = ngroups * 8 */) {
    const int j = threadIdx.x & 7;                 // lane within 8-lane cluster
    const size_t stride = (size_t)gridDim.x * blockDim.x;  // multiple of 8
    const float INV = 0.17677669529663687f;        // 1/sqrt(32)

    for (size_t s = (size_t)blockIdx.x * blockDim.x + threadIdx.x;
         s < nslots; s += stride) {
        const size_t g = s >> 3;                   // group index
        float4 v = *(const float4*)(in + g * 32 + j * 4);

        // FWHT stage s=1: pairs (x,y),(z,w)
        {
            float a = v.x, b = v.y, c = v.z, d = v.w;
            v.x = a + b; v.y = a - b; v.z = c + d; v.w = c - d;
        }
        // FWHT stage s=2: pairs (x,z),(y,w)
        {
            float a = v.x, b = v.y, c = v.z, d = v.w;
            v.x = a + c; v.z = a - c; v.y = b + d; v.w = b - d;
        }
        // FWHT stages s=4,8,16: cross-lane within the 8-lane cluster
#pragma unroll
        for (int m = 1; m <= 4; m <<= 1) {
            float px = __shfl_xor(v.x, m, 64);
            float py = __shfl_xor(v.y, m, 64);
            float pz = __shfl_xor(v.z, m, 64);
            float pw = __shfl_xor(v.w, m, 64);
            if (j & m) {
                v.x = px - v.x; v.y = py - v.y;
                v.z = pz - v.z; v.w = pw - v.w;
            } else {
                v.x = v.x + px; v.y = v.y + py;
                v.z = v.z + pz; v.w = v.w + pw;
            }
        }

        v.x *= INV; v.y *= INV; v.z *= INV; v.w *= INV;

        float amax = fmaxf(fmaxf(fabsf(v.x), fabsf(v.y)),
                           fmaxf(fabsf(v.z), fabsf(v.w)));
#pragma unroll
        for (int m = 1; m <= 4; m <<= 1)
            amax = fmaxf(amax, __shfl_xor(amax, m, 64));

        // e = floor(log2(max(amax, 2^-126))) - 2, clipped to [-127,127].
        // Exact via exponent-field extraction (amax >= 0).
        int ex = (int)(__float_as_uint(amax) >> 23) - 127;
        if (ex < -126) ex = -126;                  // zero/subnormal -> -126
        int e = ex - 2;
        if (e < -127) e = -127;
        float scale  = __uint_as_float((unsigned)(e + 127) << 23);  // 2^e
        float rscale = __uint_as_float((unsigned)(127 - e) << 23);  // 2^-e

        ushort4 o;
        float elems[4] = {v.x, v.y, v.z, v.w};
        unsigned short* po = (unsigned short*)&o;
#pragma unroll
        for (int i = 0; i < 4; ++i) {
            float sv = elems[i] * rscale;          // == v/scale exactly
            float a = fminf(fabsf(sv), 6.0f);
            // idx = sum(a > mids), strict > (ties toward zero), as reference
            float q = a > 0.25f ? (a > 0.75f ? (a > 1.25f ? (a > 1.75f ?
                      (a > 2.5f ? (a > 3.5f ? (a > 5.0f ? 6.f : 4.f) : 3.f) : 2.f)
                      : 1.5f) : 1.f) : 0.5f) : 0.f;
            float r = copysignf(q, sv) * scale;    // exact in f32 and bf16
            po[i] = (unsigned short)(__float_as_uint(r) >> 16);
        }
        *(ushort4*)(out + g * 32 + j * 4) = o;     // 8B contiguous store
    }
}

// ---------------------------------------------------------------------------
// Kernel 2: C[M,N] = A[M,K](bf16) * B[N,K](bf16)^T + bias[N], f32 out
// m97 structure: 128x128 tile, BK=32, 4 waves (2x2), 4x4 16x16x32 frags/wave,
// global_load_lds width 16, 2-barrier loop, XCD-aware block swizzle.
// ---------------------------------------------------------------------------
#define GBM 128
#define GBN 128
#define GBK 32

__global__ void gemm_bt_kernel(const unsigned short* __restrict__ A,
                               const unsigned short* __restrict__ B,
                               const float* __restrict__ bias,
                               float* __restrict__ C,
                               int M, int N, int K) {
    __shared__ unsigned short sA[GBM * GBK];
    __shared__ unsigned short sB[GBN * GBK];

    int nbn = N / GBN;
    int nwg = (M / GBM) * nbn;
    int bid = blockIdx.x;
    int swz;
    if ((nwg & 7) == 0) {                   // bijective XCD swizzle
        int cpx = nwg >> 3;
        swz = (bid & 7) * cpx + (bid >> 3);
    } else {
        swz = bid;
    }
    int bm = swz / nbn, bn = swz % nbn;

    int t = threadIdx.x;
    int lane = t & 63;
    int wid = t >> 6;
    int wr = wid >> 1, wc = wid & 1;        // 2x2 wave grid, 64x64 out each
    int fr = lane & 15, fq = lane >> 4;     // fragment row / k-chunk

    f32x4 acc[4][4] = {};

    // staging: thread t covers LDS bytes t*16 (linear), rows t>>2, kchunk t&3
    const unsigned short* gA = A + (size_t)bm * GBM * K + (size_t)(t >> 2) * K + (t & 3) * 8;
    const unsigned short* gB = B + (size_t)bn * GBN * K + (size_t)(t >> 2) * K + (t & 3) * 8;
    unsigned short* sAp = sA + t * 8;
    unsigned short* sBp = sB + t * 8;
    const size_t rowStep = (size_t)64 * K;

    for (int kb = 0; kb < K; kb += GBK) {
        __syncthreads();  // previous compute done before overwrite
        __builtin_amdgcn_global_load_lds(AS1C(gA + kb),           AS3(sAp),        16, 0, 0);
        __builtin_amdgcn_global_load_lds(AS1C(gA + kb + rowStep), AS3(sAp + 2048), 16, 0, 0);
        __builtin_amdgcn_global_load_lds(AS1C(gB + kb),           AS3(sBp),        16, 0, 0);
        __builtin_amdgcn_global_load_lds(AS1C(gB + kb + rowStep), AS3(sBp + 2048), 16, 0, 0);
        __syncthreads();  // compiler drains vmcnt before s_barrier

        bf16x8 af[4], bfr[4];
#pragma unroll
        for (int m = 0; m < 4; ++m)
            af[m] = *(const bf16x8*)&sA[(wr * 64 + m * 16 + fr) * GBK + fq * 8];
#pragma unroll
        for (int n = 0; n < 4; ++n)
            bfr[n] = *(const bf16x8*)&sB[(wc * 64 + n * 16 + fr) * GBK + fq * 8];

#pragma unroll
        for (int m = 0; m < 4; ++m)
#pragma unroll
            for (int n = 0; n < 4; ++n)
                acc[m][n] = __builtin_amdgcn_mfma_f32_16x16x32_bf16(
                    af[m], bfr[n], acc[m][n], 0, 0, 0);
    }

    // C/D layout (verified m89/m91): col = lane&15, row = (lane>>4)*4 + reg
    int row0 = bm * GBM + wr * 64 + fq * 4;
    int col0 = bn * GBN + wc * 64 + fr;
#pragma unroll
    for (int m = 0; m < 4; ++m) {
#pragma unroll
        for (int n = 0; n < 4; ++n) {
            int c = col0 + n * 16;
            float bv = bias[c];
#pragma unroll
            for (int j = 0; j < 4; ++j) {
                int r = row0 + m * 16 + j;
                C[(size_t)r * N + c] = acc[m][n][j] + bv;
            }
        }
    }
}

// ---------------------------------------------------------------------------
extern "C" void kernel_launch(void* const* d_in, const int* in_sizes, int n_in,
                              void* d_out, int out_size, void* d_ws, size_t ws_size,
                              hipStream_t stream) {
    const float* x    = (const float*)d_in[0];
    const float* w    = (const float*)d_in[1];
    const float* bias = (const float*)d_in[2];
    // d_in[3] (hadamard matrix) is Sylvester/sqrt(32): implemented as FWHT.

    int N = in_sizes[2];            // 4096
    int K = in_sizes[1] / N;        // 4096
    int M = in_sizes[0] / K;        // 8192

    unsigned short* xq = (unsigned short*)d_ws;
    unsigned short* wq = xq + (size_t)M * K;

    size_t nsx = ((size_t)M * K / 32) * 8;   // slots = groups * 8
    size_t nsw = ((size_t)N * K / 32) * 8;

    int gx = (int)(((nsx + 255) / 256) < 4096 ? ((nsx + 255) / 256) : 4096);
    int gw = (int)(((nsw + 255) / 256) < 4096 ? ((nsw + 255) / 256) : 4096);

    rotquant_kernel<<<dim3(gx), dim3(256), 0, stream>>>(x, xq, nsx);
    rotquant_kernel<<<dim3(gw), dim3(256), 0, stream>>>(w, wq, nsw);

    int grid = (M / GBM) * (N / GBN);
    gemm_bt_kernel<<<dim3(grid), dim3(256), 0, stream>>>(xq, wq, bias, (float*)d_out, M, N, K);
}